// Round 16
// baseline (430.523 us; speedup 1.0000x reference)
//
#include <hip/hip_runtime.h>
#include <cstdint>
#include <cstddef>

typedef unsigned short u16;
typedef __attribute__((ext_vector_type(8))) short short8;
typedef __attribute__((ext_vector_type(4))) float f32x4;
typedef __attribute__((ext_vector_type(16))) float f32x16;

#define DIM 512
#define C2  256
#define HD  32
#define SCALE_Q 0.17677669529663689f

__device__ __forceinline__ float bf2f(u16 u){ return __uint_as_float(((unsigned)u) << 16); }
__device__ __forceinline__ u16 f2bf(float f){
  unsigned u = __float_as_uint(f);
  unsigned r = (u + 0x7FFFu + ((u >> 16) & 1u)) >> 16;
  return (u16)r;
}

__device__ __forceinline__ f32x4 mfma16(short8 a, short8 b, f32x4 c){
  return __builtin_amdgcn_mfma_f32_16x16x32_bf16(a, b, c, 0, 0, 0);
}
__device__ __forceinline__ f32x16 mfma32(short8 a, short8 b, f32x16 c){
  return __builtin_amdgcn_mfma_f32_32x32x16_bf16(a, b, c, 0, 0, 0);
}

// async global->LDS, 16 bytes per lane; LDS dest is wave-uniform base (+lane*16 implied)
__device__ __forceinline__ void gload16(const u16* g, u16* l){
  __builtin_amdgcn_global_load_lds((const __attribute__((address_space(1))) void*)g,
                                   (__attribute__((address_space(3))) void*)l, 16, 0, 0);
}

// fast gelu: v * sigmoid(1.702 v)
__device__ __forceinline__ float gelu_f(float v){
  float e = __expf(-1.702f * v);
  return v * __builtin_amdgcn_rcpf(1.0f + e);
}

// ---------------- merged weight transposes (4 matrices, one launch) ----------------
__global__ __launch_bounds__(256) void transpose_all_kernel(
    const float* __restrict__ qkv_w, const float* __restrict__ proj_w,
    const float* __restrict__ fc1_w, const float* __restrict__ fc2_w,
    u16* __restrict__ qkv_wT, u16* __restrict__ proj_wT,
    u16* __restrict__ fc1_wT, u16* __restrict__ fc2_wT){
  __shared__ u16 Tl[32][33];
  int b = blockIdx.x;
  const float* W; u16* WT; int K, N, nx, ti;
  if (b < 192)      { W = qkv_w;  WT = qkv_wT;  K = 256;  N = 768;  nx = 24; ti = b; }
  else if (b < 448) { W = proj_w; WT = proj_wT; K = 512;  N = 512;  nx = 16; ti = b - 192; }
  else if (b < 1472){ W = fc1_w;  WT = fc1_wT;  K = 512;  N = 2048; nx = 64; ti = b - 448; }
  else              { W = fc2_w;  WT = fc2_wT;  K = 2048; N = 512;  nx = 16; ti = b - 1472; }
  int n0 = (ti % nx) * 32, k0 = (ti / nx) * 32;
  int tx = threadIdx.x & 31, ty = threadIdx.x >> 5;
#pragma unroll
  for (int i = 0; i < 4; i++){
    int k = ty * 4 + i;
    Tl[k][tx] = f2bf(W[(size_t)(k0 + k) * N + n0 + tx]);
  }
  __syncthreads();
#pragma unroll
  for (int i = 0; i < 4; i++){
    int n = ty * 4 + i;
    WT[(size_t)(n0 + n) * K + k0 + tx] = Tl[tx][n];
  }
}

// ---------------- LayerNorm, one wave per row; fp32 in -> bf16 out ----------------
__global__ __launch_bounds__(256) void ln_kernel(const float* __restrict__ x, const float* __restrict__ g,
                                                 const float* __restrict__ bta, u16* __restrict__ out){
  int row  = blockIdx.x * 4 + (threadIdx.x >> 6);
  int lane = threadIdx.x & 63;
  size_t base = (size_t)row * DIM + lane * 8;
  float4 v0 = *(const float4*)(x + base);
  float4 v1 = *(const float4*)(x + base + 4);
  float f[8] = {v0.x, v0.y, v0.z, v0.w, v1.x, v1.y, v1.z, v1.w};
  float s = 0.f;
#pragma unroll
  for (int j = 0; j < 8; j++) s += f[j];
#pragma unroll
  for (int m = 1; m < 64; m <<= 1) s += __shfl_xor(s, m, 64);
  float mean = s * (1.0f / DIM);
  float vs = 0.f;
#pragma unroll
  for (int j = 0; j < 8; j++){ float d = f[j] - mean; vs += d * d; }
#pragma unroll
  for (int m = 1; m < 64; m <<= 1) vs += __shfl_xor(vs, m, 64);
  float rstd = rsqrtf(vs * (1.0f / DIM) + 1e-5f);
  float4 g0 = *(const float4*)(g + lane * 8);
  float4 g1 = *(const float4*)(g + lane * 8 + 4);
  float4 b0 = *(const float4*)(bta + lane * 8);
  float4 b1 = *(const float4*)(bta + lane * 8 + 4);
  float gg[8] = {g0.x, g0.y, g0.z, g0.w, g1.x, g1.y, g1.z, g1.w};
  float bb[8] = {b0.x, b0.y, b0.z, b0.w, b1.x, b1.y, b1.z, b1.w};
  short8 o;
#pragma unroll
  for (int j = 0; j < 8; j++){
    float r = (f[j] - mean) * rstd * gg[j] + bb[j];
    o[j] = (short)f2bf(r);
  }
  *(short8*)(out + base) = o;
}

// ---------------- GEMM: 256x256 tile, R8 schedule, 32x32x16 MFMA ----------------
// C[M x N] = A[M x K] @ W[K x N] (+bias, +epilogue); A bf16 RM (lda); WT bf16 [N x K] RM.
// 8 waves (2M x 4N), per-wave C = 128x64 as 4x2 blocks of 32x32. BK=64, two kh of 32,
// each kh = two k-steps of 16. LDS [2][2][256][32] per matrix (128 KB), slot-swizzled.
// Frag (A and B operands): lane holds [idx = lane&31][k = (lane>>5)*8 .. +8] (b128 read).
// Swapped operands: acc = mfma32(bf, af) -> lane holds C[row = lane&31 (+32*rb)]
// [col = g*8 + (lane>>5)*4 + {0..3}] per reg-quad g -> direct float4 epilogue.
// Schedule/stage placements verbatim R8 (phases now (kh, mh)):
//   P1(kh0,mh0)  P2(kh0,mh1)+stageB(t+2,kh0)  P3(kh1,mh0)+stageA(t+2,kh0)
//   P4(kh1,mh1)+stageB(t+2,kh1)  post: stageA(t+2,kh1); vmcnt(8) (0 at tail); barrier.
// Safety: each staged region's last ds_read is >=1 closing barrier before the stage.
template<int EPI, bool OUT_BF16>
__device__ __forceinline__ void gemm8_body(
    const u16* __restrict__ A, int lda,
    const u16* __restrict__ WT,
    const float* __restrict__ bias,
    const float* R, int ldr,
    void* Cv, int ldc, int K)
{
  __shared__ u16 Al[2][2][256 * 32];
  __shared__ u16 Bl[2][2][256 * 32];
  const int tid = threadIdx.x;
  const int l   = tid & 63;
  const int w   = tid >> 6;
  const int wr  = w >> 2;          // M half
  const int wc  = w & 3;           // N quarter
  const int l31 = l & 31, lh2 = l >> 5;

  const int gx = gridDim.x;
  int bid = blockIdx.y * gx + blockIdx.x;
  int nwg = gx * gridDim.y;
  int sw  = (nwg & 7) ? bid : ((bid & 7) * (nwg >> 3) + (bid >> 3));
  const int col0 = (sw % gx) * 256, row0 = (sw / gx) * 256;
  const int NT = K >> 6;

  const int srow = w * 16 + (l >> 2);
  const int cs   = (((l & 3) ^ ((l >> 3) & 3)) * 8);
  const u16* pA = A  + (size_t)(row0 + srow) * lda + cs;
  const u16* pB = WT + (size_t)(col0 + srow) * K  + cs;
  const size_t a128 = (size_t)128 * lda, b128 = (size_t)128 * K;

  auto stageA = [&](int tt, int hh){
    if (tt < NT){
      size_t go = (size_t)tt * 64 + (size_t)hh * 32;
      gload16(pA + go,        &Al[tt & 1][hh][(w * 16) * 32]);
      gload16(pA + a128 + go, &Al[tt & 1][hh][(128 + w * 16) * 32]);
    }
  };
  auto stageB = [&](int tt, int hh){
    if (tt < NT){
      size_t go = (size_t)tt * 64 + (size_t)hh * 32;
      gload16(pB + go,        &Bl[tt & 1][hh][(w * 16) * 32]);
      gload16(pB + b128 + go, &Bl[tt & 1][hh][(128 + w * 16) * 32]);
    }
  };

  // ds_read addr inside a [256][32] region for frag (row, kstep-within-kh ks01):
  // slot = ks01*2 + lh2, swizzled by row bits 1..2 (both-sides rule).
  auto rdaddr = [&](int row, int ks01){
    int slot = (ks01 * 2 + lh2) ^ ((row >> 1) & 3);
    return row * 32 + slot * 8;
  };

  f32x16 acc[4][2] = {};
  short8 af[4], bf[4];

  stageA(0, 0); stageB(0, 0); stageA(0, 1); stageB(0, 1);
  stageA(1, 0); stageB(1, 0); stageA(1, 1); stageB(1, 1);
  asm volatile("s_waitcnt vmcnt(8)" ::: "memory");
  __builtin_amdgcn_sched_barrier(0);
  __builtin_amdgcn_s_barrier();

#define PHASE(BC, KH, MH, STAGES) do{                                                   \
    if ((MH) == 0){                                                                     \
      _Pragma("unroll")                                                                 \
      for (int j = 0; j < 4; j++)                                                       \
        bf[j] = *(const short8*)&Bl[BC][KH][rdaddr(wc * 64 + (j >> 1) * 32 + l31, j & 1)]; \
    }                                                                                   \
    _Pragma("unroll")                                                                   \
    for (int j = 0; j < 4; j++)                                                         \
      af[j] = *(const short8*)&Al[BC][KH][rdaddr(wr * 128 + (MH) * 64 + (j >> 1) * 32 + l31, j & 1)]; \
    STAGES;                                                                             \
    __builtin_amdgcn_s_barrier();                                                       \
    asm volatile("s_waitcnt lgkmcnt(0)" ::: "memory");                                  \
    __builtin_amdgcn_sched_barrier(0);                                                  \
    __builtin_amdgcn_s_setprio(1);                                                      \
    _Pragma("unroll")                                                                   \
    for (int rb = 0; rb < 2; rb++)                                                      \
      _Pragma("unroll")                                                                 \
      for (int cb = 0; cb < 2; cb++)                                                    \
        _Pragma("unroll")                                                               \
        for (int ks = 0; ks < 2; ks++)                                                  \
          acc[(MH) * 2 + rb][cb] = mfma32(bf[cb * 2 + ks], af[rb * 2 + ks], acc[(MH) * 2 + rb][cb]); \
    __builtin_amdgcn_s_setprio(0);                                                      \
    __builtin_amdgcn_s_barrier();                                                       \
  }while(0)

  for (int t = 0; t < NT; t++){
    const int bc = t & 1;
    PHASE(bc, 0, 0, (void)0);
    PHASE(bc, 0, 1, stageB(t + 2, 0));
    PHASE(bc, 1, 0, stageA(t + 2, 0));
    PHASE(bc, 1, 1, stageB(t + 2, 1));
    stageA(t + 2, 1);
    if (t + 2 < NT) asm volatile("s_waitcnt vmcnt(8)" ::: "memory");
    else            asm volatile("s_waitcnt vmcnt(0)" ::: "memory");
    __builtin_amdgcn_sched_barrier(0);
    __builtin_amdgcn_s_barrier();
  }
#undef PHASE

  // ---- epilogue: lane owns row = rb*32 + l31; cols = cb*32 + g*8 + lh2*4 + {0..3} ----
#pragma unroll
  for (int rb = 0; rb < 4; rb++){
    int grow = row0 + wr * 128 + rb * 32 + l31;
#pragma unroll
    for (int cb = 0; cb < 2; cb++){
#pragma unroll
      for (int g = 0; g < 4; g++){
        int gcol = col0 + wc * 64 + cb * 32 + g * 8 + lh2 * 4;
        float4 bb = *(const float4*)&bias[gcol];
        float4 vv = { acc[rb][cb][g * 4 + 0] + bb.x, acc[rb][cb][g * 4 + 1] + bb.y,
                      acc[rb][cb][g * 4 + 2] + bb.z, acc[rb][cb][g * 4 + 3] + bb.w };
        if constexpr (EPI == 1){
          float4 rv = *(const float4*)&R[(size_t)grow * ldr + gcol];
          vv.x += rv.x; vv.y += rv.y; vv.z += rv.z; vv.w += rv.w;
        }
        if constexpr (EPI == 2){
          vv.x = gelu_f(vv.x); vv.y = gelu_f(vv.y); vv.z = gelu_f(vv.z); vv.w = gelu_f(vv.w);
        }
        if constexpr (OUT_BF16){
          ushort4 o4 = { f2bf(vv.x), f2bf(vv.y), f2bf(vv.z), f2bf(vv.w) };
          *(ushort4*)&((u16*)Cv)[(size_t)grow * ldc + gcol] = o4;
        } else {
          *(float4*)&((float*)Cv)[(size_t)grow * ldc + gcol] = vv;
        }
      }
    }
  }
}

__global__ __launch_bounds__(512, 2) void gemm_qkv_kernel(const u16* A, int lda, const u16* WT,
    const float* bias, const float* R, int ldr, void* Cv, int ldc, int K){
  gemm8_body<0, true>(A, lda, WT, bias, R, ldr, Cv, ldc, K);
}
__global__ __launch_bounds__(512, 2) void gemm_proj_kernel(const u16* A, int lda, const u16* WT,
    const float* bias, const float* R, int ldr, void* Cv, int ldc, int K){
  gemm8_body<1, false>(A, lda, WT, bias, R, ldr, Cv, ldc, K);
}
__global__ __launch_bounds__(512, 2) void gemm_fc1_kernel(const u16* A, int lda, const u16* WT,
    const float* bias, const float* R, int ldr, void* Cv, int ldc, int K){
  gemm8_body<2, true>(A, lda, WT, bias, R, ldr, Cv, ldc, K);
}
__global__ __launch_bounds__(512, 2) void gemm_fc2_kernel(const u16* A, int lda, const u16* WT,
    const float* bias, const float* R, int ldr, void* Cv, int ldc, int K){
  gemm8_body<1, false>(A, lda, WT, bias, R, ldr, Cv, ldc, K);
}

// ---------------- MFMA windowed attention + LePE (unchanged from R15) ----------------
__global__ __launch_bounds__(256) void attn_kernel(
    const u16* __restrict__ qkv, const float* __restrict__ lw,
    const float* __restrict__ lb, u16* __restrict__ out)
{
  __shared__ u16  Vt[4][32 * 76];
  __shared__ u16  Pl[4][64 * 76];
  __shared__ float Wl[9 * 256];
  __shared__ float Lb[256];
  const int tid = threadIdx.x;
  const int l   = tid & 63;
  const int w   = tid >> 6;
  const int l16 = l & 15, lhi = l >> 4;

  int win = blockIdx.x;
  int wx = win & 7, wy = (win >> 3) & 7, b = win >> 6;
  auto trow = [&](int tok){
    return (size_t)b * 4096 + (size_t)(wy * 8 + (tok >> 3)) * 64 + (wx * 8 + (tok & 7));
  };

  for (int i = tid; i < 2304; i += 256){
    int ch = i / 9, tp = i - ch * 9;
    Wl[tp * 256 + ch] = lw[i];
  }
  if (tid < 256) Lb[tid] = lb[tid];
  __syncthreads();

  u16* vt = Vt[w];
  u16* pl = Pl[w];

  for (int hi = 0; hi < 2; hi++){
    const int h = w + hi * 4;
    const int co = h * HD;

    {
      const u16* vp = qkv + trow(l) * 768 + 512 + co;
#pragma unroll
      for (int j = 0; j < 4; j++){
        short8 v8 = *(const short8*)(vp + j * 8);
#pragma unroll
        for (int e = 0; e < 8; e++)
          vt[(j * 8 + e) * 76 + l] = (u16)v8[e];
      }
    }

    short8 Qf[4], Kf[4];
#pragma unroll
    for (int m = 0; m < 4; m++){
      size_t r = trow(m * 16 + l16) * 768;
      Qf[m] = *(const short8*)(qkv + r + co + lhi * 8);
      Kf[m] = *(const short8*)(qkv + r + 256 + co + lhi * 8);
    }

    f32x4 s[4][4];
#pragma unroll
    for (int m = 0; m < 4; m++)
#pragma unroll
      for (int n = 0; n < 4; n++){
        f32x4 z = {0.f, 0.f, 0.f, 0.f};
        s[m][n] = mfma16(Kf[n], Qf[m], z);
      }

    float mx[4], sum[4], inv[4];
#pragma unroll
    for (int m = 0; m < 4; m++){
      float mm = -1e30f;
#pragma unroll
      for (int n = 0; n < 4; n++)
#pragma unroll
        for (int i = 0; i < 4; i++){
          s[m][n][i] *= SCALE_Q;
          mm = fmaxf(mm, s[m][n][i]);
        }
      mm = fmaxf(mm, __shfl_xor(mm, 16, 64));
      mm = fmaxf(mm, __shfl_xor(mm, 32, 64));
      mx[m] = mm;
      float ss = 0.f;
#pragma unroll
      for (int n = 0; n < 4; n++)
#pragma unroll
        for (int i = 0; i < 4; i++){
          float e = __expf(s[m][n][i] - mm);
          s[m][n][i] = e;
          ss += e;
        }
      ss += __shfl_xor(ss, 16, 64);
      ss += __shfl_xor(ss, 32, 64);
      sum[m] = ss;
      inv[m] = __builtin_amdgcn_rcpf(ss);
    }

#pragma unroll
    for (int m = 0; m < 4; m++){
      int q = m * 16 + l16;
#pragma unroll
      for (int n = 0; n < 4; n++){
        ushort4 p4 = { f2bf(s[m][n][0] * inv[m]), f2bf(s[m][n][1] * inv[m]),
                       f2bf(s[m][n][2] * inv[m]), f2bf(s[m][n][3] * inv[m]) };
        *(ushort4*)&pl[q * 76 + n * 16 + lhi * 4] = p4;
      }
    }
    short8 Pf[4][2], Vf[2][2];
#pragma unroll
    for (int m = 0; m < 4; m++)
#pragma unroll
      for (int st = 0; st < 2; st++)
        Pf[m][st] = *(const short8*)&pl[(m * 16 + l16) * 76 + st * 32 + lhi * 8];
#pragma unroll
    for (int df = 0; df < 2; df++)
#pragma unroll
      for (int st = 0; st < 2; st++)
        Vf[df][st] = *(const short8*)&vt[(df * 16 + l16) * 76 + st * 32 + lhi * 8];

    f32x4 o[4][2];
#pragma unroll
    for (int m = 0; m < 4; m++)
#pragma unroll
      for (int df = 0; df < 2; df++){
        f32x4 z = {0.f, 0.f, 0.f, 0.f};
        z = mfma16(Vf[df][0], Pf[m][0], z);
        o[m][df] = mfma16(Vf[df][1], Pf[m][1], z);
      }

#pragma unroll
    for (int m = 0; m < 4; m++){
      int q = m * 16 + l16;
      int py = q >> 3, px = q & 7;
#pragma unroll
      for (int df = 0; df < 2; df++){
        int dd = df * 16 + lhi * 4;
#pragma unroll
        for (int ky = 0; ky < 3; ky++){
          int yy = py + ky - 1;
          if (yy < 0 || yy >= 8) continue;
#pragma unroll
          for (int kx = 0; kx < 3; kx++){
            int xx = px + kx - 1;
            if (xx < 0 || xx >= 8) continue;
            int kp = yy * 8 + xx;
            ushort4 v4 = *(const ushort4*)(qkv + trow(kp) * 768 + 512 + co + dd);
            float4 wv = *(const float4*)&Wl[(ky * 3 + kx) * 256 + co + dd];
            o[m][df][0] += wv.x * bf2f(v4.x);
            o[m][df][1] += wv.y * bf2f(v4.y);
            o[m][df][2] += wv.z * bf2f(v4.z);
            o[m][df][3] += wv.w * bf2f(v4.w);
          }
        }
        float4 lbv = *(const float4*)&Lb[co + dd];
        ushort4 o4 = { f2bf(o[m][df][0] + lbv.x), f2bf(o[m][df][1] + lbv.y),
                       f2bf(o[m][df][2] + lbv.z), f2bf(o[m][df][3] + lbv.w) };
        *(ushort4*)&out[trow(q) * DIM + co + dd] = o4;
      }
    }
  }
}

// ---------------- full-image depthwise 3x3, vectorized (unchanged from R14) ----------------
__global__ __launch_bounds__(256) void convloc_kernel(const u16* __restrict__ img,
    const float* __restrict__ w, u16* __restrict__ out){
  __shared__ float Wl[9 * 256];
  int tid = threadIdx.x;
  for (int i = tid; i < 2304; i += 256){
    int ch = i / 9, tp = i - ch * 9;
    Wl[tp * 256 + ch] = w[i];
  }
  __syncthreads();
  int c  = (tid & 63) * 4;
  int pq = tid >> 6;
  int p  = blockIdx.x * 4 + pq;
  int b  = p >> 12;
  int pi = p & 4095;
  int y = pi >> 6, x = pi & 63;
  float a0 = 0.f, a1 = 0.f, a2 = 0.f, a3 = 0.f;
#pragma unroll
  for (int ky = 0; ky < 3; ky++){
    int yy = y + ky - 1;
    if (yy < 0 || yy >= 64) continue;
#pragma unroll
    for (int kx = 0; kx < 3; kx++){
      int xx = x + kx - 1;
      if (xx < 0 || xx >= 64) continue;
      ushort4 v = *(const ushort4*)&img[((size_t)b * 4096 + yy * 64 + xx) * DIM + C2 + c];
      float4 wv = *(const float4*)&Wl[(ky * 3 + kx) * 256 + c];
      a0 += wv.x * bf2f(v.x); a1 += wv.y * bf2f(v.y);
      a2 += wv.z * bf2f(v.z); a3 += wv.w * bf2f(v.w);
    }
  }
  ushort4 o4 = { f2bf(a0), f2bf(a1), f2bf(a2), f2bf(a3) };
  *(ushort4*)&out[((size_t)b * 4096 + pi) * DIM + C2 + c] = o4;
}

extern "C" void kernel_launch(void* const* d_in, const int* in_sizes, int n_in,
                              void* d_out, int out_size, void* d_ws, size_t ws_size,
                              hipStream_t stream){
  const float* x      = (const float*)d_in[0];
  const float* n1g    = (const float*)d_in[1];
  const float* n1b    = (const float*)d_in[2];
  const float* qkv_w  = (const float*)d_in[3];
  const float* qkv_b  = (const float*)d_in[4];
  const float* lepe_w = (const float*)d_in[5];
  const float* lepe_b = (const float*)d_in[6];
  const float* conv_w = (const float*)d_in[7];
  const float* proj_w = (const float*)d_in[8];
  const float* proj_b = (const float*)d_in[9];
  const float* n2g    = (const float*)d_in[10];
  const float* n2b    = (const float*)d_in[11];
  const float* fc1_w  = (const float*)d_in[12];
  const float* fc1_b  = (const float*)d_in[13];
  const float* fc2_w  = (const float*)d_in[14];
  const float* fc2_b  = (const float*)d_in[15];
  float* out = (float*)d_out;

  char* ws = (char*)d_ws;
  u16* img     = (u16*)(ws + 0);
  u16* qkvb    = (u16*)(ws + 33554432ull);
  u16* localb  = (u16*)(ws + 83886080ull);
  u16* y       = (u16*)(ws + 0);          // reuses img (dead after convloc)
  u16* h       = (u16*)(ws + 33554432ull);
  u16* qkv_wT  = (u16*)(ws + 167772160ull);
  u16* proj_wT = (u16*)(ws + 167772160ull + 393216ull);
  u16* fc1_wT  = (u16*)(ws + 167772160ull + 393216ull + 524288ull);
  u16* fc2_wT  = (u16*)(ws + 167772160ull + 393216ull + 524288ull + 2097152ull);
  float* xa    = (float*)d_out;

  transpose_all_kernel<<<2496, 256, 0, stream>>>(qkv_w, proj_w, fc1_w, fc2_w,
                                                 qkv_wT, proj_wT, fc1_wT, fc2_wT);

  ln_kernel<<<8192, 256, 0, stream>>>(x, n1g, n1b, img);

  dim3 gq(3, 128);
  gemm_qkv_kernel<<<gq, 512, 0, stream>>>(img, DIM, qkv_wT, qkv_b, nullptr, 0, qkvb, 768, 256);

  attn_kernel<<<512, 256, 0, stream>>>(qkvb, lepe_w, lepe_b, localb);
  convloc_kernel<<<8192, 256, 0, stream>>>(img, conv_w, localb);

  dim3 gp(2, 128);
  gemm_proj_kernel<<<gp, 512, 0, stream>>>(localb, DIM, proj_wT, proj_b, x, DIM, xa, DIM, 512);

  ln_kernel<<<8192, 256, 0, stream>>>(xa, n2g, n2b, y);

  dim3 g1(8, 128);
  gemm_fc1_kernel<<<g1, 512, 0, stream>>>(y, DIM, fc1_wT, fc1_b, nullptr, 0, h, 2048, 512);

  dim3 g2(2, 128);
  gemm_fc2_kernel<<<g2, 512, 0, stream>>>(h, 2048, fc2_wT, fc2_b, xa, DIM, out, DIM, 2048);
}

// Round 17
// 385.522 us; speedup vs baseline: 1.1167x; 1.1167x over previous
//
#include <hip/hip_runtime.h>
#include <cstdint>
#include <cstddef>

typedef unsigned short u16;
typedef __attribute__((ext_vector_type(8))) short short8;
typedef __attribute__((ext_vector_type(4))) float f32x4;

#define DIM 512
#define C2  256
#define HD  32
#define SCALE_Q 0.17677669529663689f

__device__ __forceinline__ float bf2f(u16 u){ return __uint_as_float(((unsigned)u) << 16); }
__device__ __forceinline__ u16 f2bf(float f){
  unsigned u = __float_as_uint(f);
  unsigned r = (u + 0x7FFFu + ((u >> 16) & 1u)) >> 16;
  return (u16)r;
}

__device__ __forceinline__ f32x4 mfma16(short8 a, short8 b, f32x4 c){
  return __builtin_amdgcn_mfma_f32_16x16x32_bf16(a, b, c, 0, 0, 0);
}

// async global->LDS, 16 bytes per lane; LDS dest is wave-uniform base (+lane*16 implied)
__device__ __forceinline__ void gload16(const u16* g, u16* l){
  __builtin_amdgcn_global_load_lds((const __attribute__((address_space(1))) void*)g,
                                   (__attribute__((address_space(3))) void*)l, 16, 0, 0);
}

// fast gelu: v * sigmoid(1.702 v)
__device__ __forceinline__ float gelu_f(float v){
  float e = __expf(-1.702f * v);
  return v * __builtin_amdgcn_rcpf(1.0f + e);
}

// ---------------- merged: 4 weight transposes + LN1, one launch ----------------
// blocks [0,2496): transpose; [2496, 2496+8192): LN1 (4 rows/block).
__global__ __launch_bounds__(256) void prep_kernel(
    const float* __restrict__ qkv_w, const float* __restrict__ proj_w,
    const float* __restrict__ fc1_w, const float* __restrict__ fc2_w,
    u16* __restrict__ qkv_wT, u16* __restrict__ proj_wT,
    u16* __restrict__ fc1_wT, u16* __restrict__ fc2_wT,
    const float* __restrict__ x, const float* __restrict__ n1g,
    const float* __restrict__ n1b, u16* __restrict__ img){
  __shared__ u16 Tl[32][33];
  int blk = blockIdx.x;
  if (blk < 2496){
    const float* W; u16* WT; int K, N, nx, ti;
    if (blk < 192)      { W = qkv_w;  WT = qkv_wT;  K = 256;  N = 768;  nx = 24; ti = blk; }
    else if (blk < 448) { W = proj_w; WT = proj_wT; K = 512;  N = 512;  nx = 16; ti = blk - 192; }
    else if (blk < 1472){ W = fc1_w;  WT = fc1_wT;  K = 512;  N = 2048; nx = 64; ti = blk - 448; }
    else                { W = fc2_w;  WT = fc2_wT;  K = 2048; N = 512;  nx = 16; ti = blk - 1472; }
    int n0 = (ti % nx) * 32, k0 = (ti / nx) * 32;
    int tx = threadIdx.x & 31, ty = threadIdx.x >> 5;
#pragma unroll
    for (int i = 0; i < 4; i++){
      int k = ty * 4 + i;
      Tl[k][tx] = f2bf(W[(size_t)(k0 + k) * N + n0 + tx]);
    }
    __syncthreads();
#pragma unroll
    for (int i = 0; i < 4; i++){
      int n = ty * 4 + i;
      WT[(size_t)(n0 + n) * K + k0 + tx] = Tl[tx][n];
    }
  } else {
    int row  = (blk - 2496) * 4 + (threadIdx.x >> 6);
    int lane = threadIdx.x & 63;
    size_t base = (size_t)row * DIM + lane * 8;
    float4 v0 = *(const float4*)(x + base);
    float4 v1 = *(const float4*)(x + base + 4);
    float f[8] = {v0.x, v0.y, v0.z, v0.w, v1.x, v1.y, v1.z, v1.w};
    float s = 0.f;
#pragma unroll
    for (int j = 0; j < 8; j++) s += f[j];
#pragma unroll
    for (int m = 1; m < 64; m <<= 1) s += __shfl_xor(s, m, 64);
    float mean = s * (1.0f / DIM);
    float vs = 0.f;
#pragma unroll
    for (int j = 0; j < 8; j++){ float d = f[j] - mean; vs += d * d; }
#pragma unroll
    for (int m = 1; m < 64; m <<= 1) vs += __shfl_xor(vs, m, 64);
    float rstd = rsqrtf(vs * (1.0f / DIM) + 1e-5f);
    float4 g0 = *(const float4*)(n1g + lane * 8);
    float4 g1 = *(const float4*)(n1g + lane * 8 + 4);
    float4 b0 = *(const float4*)(n1b + lane * 8);
    float4 b1 = *(const float4*)(n1b + lane * 8 + 4);
    float gg[8] = {g0.x, g0.y, g0.z, g0.w, g1.x, g1.y, g1.z, g1.w};
    float bb[8] = {b0.x, b0.y, b0.z, b0.w, b1.x, b1.y, b1.z, b1.w};
    short8 o;
#pragma unroll
    for (int j = 0; j < 8; j++){
      float r = (f[j] - mean) * rstd * gg[j] + bb[j];
      o[j] = (short)f2bf(r);
    }
    *(short8*)(img + base) = o;
  }
}

// ---------------- LayerNorm (LN2), one wave per row; fp32 in -> bf16 out ----------------
__global__ __launch_bounds__(256) void ln_kernel(const float* __restrict__ x, const float* __restrict__ g,
                                                 const float* __restrict__ bta, u16* __restrict__ out){
  int row  = blockIdx.x * 4 + (threadIdx.x >> 6);
  int lane = threadIdx.x & 63;
  size_t base = (size_t)row * DIM + lane * 8;
  float4 v0 = *(const float4*)(x + base);
  float4 v1 = *(const float4*)(x + base + 4);
  float f[8] = {v0.x, v0.y, v0.z, v0.w, v1.x, v1.y, v1.z, v1.w};
  float s = 0.f;
#pragma unroll
  for (int j = 0; j < 8; j++) s += f[j];
#pragma unroll
  for (int m = 1; m < 64; m <<= 1) s += __shfl_xor(s, m, 64);
  float mean = s * (1.0f / DIM);
  float vs = 0.f;
#pragma unroll
  for (int j = 0; j < 8; j++){ float d = f[j] - mean; vs += d * d; }
#pragma unroll
  for (int m = 1; m < 64; m <<= 1) vs += __shfl_xor(vs, m, 64);
  float rstd = rsqrtf(vs * (1.0f / DIM) + 1e-5f);
  float4 g0 = *(const float4*)(g + lane * 8);
  float4 g1 = *(const float4*)(g + lane * 8 + 4);
  float4 b0 = *(const float4*)(bta + lane * 8);
  float4 b1 = *(const float4*)(bta + lane * 8 + 4);
  float gg[8] = {g0.x, g0.y, g0.z, g0.w, g1.x, g1.y, g1.z, g1.w};
  float bb[8] = {b0.x, b0.y, b0.z, b0.w, b1.x, b1.y, b1.z, b1.w};
  short8 o;
#pragma unroll
  for (int j = 0; j < 8; j++){
    float r = (f[j] - mean) * rstd * gg[j] + bb[j];
    o[j] = (short)f2bf(r);
  }
  *(short8*)(out + base) = o;
}

// ---------------- GEMM (R8/R15 structure, best measured): 256x256, 4-phase, deep prefetch ----------------
template<int EPI, bool OUT_BF16>
__device__ __forceinline__ void gemm8_body(
    const u16* __restrict__ A, int lda,
    const u16* __restrict__ WT,
    const float* __restrict__ bias,
    const float* R, int ldr,
    void* Cv, int ldc, int K)
{
  __shared__ u16 Al[2][2][256 * 32];
  __shared__ u16 Bl[2][2][256 * 32];
  const int tid = threadIdx.x;
  const int l   = tid & 63;
  const int w   = tid >> 6;
  const int wr  = w >> 2;
  const int wc  = w & 3;
  const int l16 = l & 15, lhi = l >> 4;

  const int gx = gridDim.x;
  int bid = blockIdx.y * gx + blockIdx.x;
  int nwg = gx * gridDim.y;
  int sw  = (nwg & 7) ? bid : ((bid & 7) * (nwg >> 3) + (bid >> 3));
  const int col0 = (sw % gx) * 256, row0 = (sw / gx) * 256;
  const int NT = K >> 6;

  const int srow = w * 16 + (l >> 2);
  const int cs   = (((l & 3) ^ ((l >> 3) & 3)) * 8);
  const u16* pA = A  + (size_t)(row0 + srow) * lda + cs;
  const u16* pB = WT + (size_t)(col0 + srow) * K  + cs;
  const size_t a128 = (size_t)128 * lda, b128 = (size_t)128 * K;

  auto stageA = [&](int tt, int hh){
    if (tt < NT){
      size_t go = (size_t)tt * 64 + (size_t)hh * 32;
      gload16(pA + go,        &Al[tt & 1][hh][(w * 16) * 32]);
      gload16(pA + a128 + go, &Al[tt & 1][hh][(128 + w * 16) * 32]);
    }
  };
  auto stageB = [&](int tt, int hh){
    if (tt < NT){
      size_t go = (size_t)tt * 64 + (size_t)hh * 32;
      gload16(pB + go,        &Bl[tt & 1][hh][(w * 16) * 32]);
      gload16(pB + b128 + go, &Bl[tt & 1][hh][(128 + w * 16) * 32]);
    }
  };

  const int rdo = l16 * 32 + (lhi ^ ((l16 >> 1) & 3)) * 8;

  f32x4 acc[8][4] = {};
  short8 af[4], bf[4];

  stageA(0, 0); stageB(0, 0); stageA(0, 1); stageB(0, 1);
  stageA(1, 0); stageB(1, 0); stageA(1, 1); stageB(1, 1);
  asm volatile("s_waitcnt vmcnt(8)" ::: "memory");
  __builtin_amdgcn_sched_barrier(0);
  __builtin_amdgcn_s_barrier();

#define PHASE(BC, KH, QM, STAGES) do{                                                   \
    if ((QM) == 0){                                                                     \
      _Pragma("unroll")                                                                 \
      for (int n = 0; n < 4; n++)                                                       \
        bf[n] = *(const short8*)&Bl[BC][KH][(wc * 64 + n * 16) * 32 + rdo];             \
    }                                                                                   \
    _Pragma("unroll")                                                                   \
    for (int m = 0; m < 4; m++)                                                         \
      af[m] = *(const short8*)&Al[BC][KH][(wr * 128 + (QM) * 64 + m * 16) * 32 + rdo];  \
    STAGES;                                                                             \
    __builtin_amdgcn_s_barrier();                                                       \
    asm volatile("s_waitcnt lgkmcnt(0)" ::: "memory");                                  \
    __builtin_amdgcn_sched_barrier(0);                                                  \
    __builtin_amdgcn_s_setprio(1);                                                      \
    _Pragma("unroll")                                                                   \
    for (int m = 0; m < 4; m++)                                                         \
      _Pragma("unroll")                                                                 \
      for (int n = 0; n < 4; n++)                                                       \
        acc[(QM) * 4 + m][n] = mfma16(bf[n], af[m], acc[(QM) * 4 + m][n]);              \
    __builtin_amdgcn_s_setprio(0);                                                      \
    __builtin_amdgcn_s_barrier();                                                       \
  }while(0)

  for (int t = 0; t < NT; t++){
    const int bc = t & 1;
    PHASE(bc, 0, 0, (void)0);
    PHASE(bc, 0, 1, stageB(t + 2, 0));
    PHASE(bc, 1, 0, stageA(t + 2, 0));
    PHASE(bc, 1, 1, stageB(t + 2, 1));
    stageA(t + 2, 1);
    if (t + 2 < NT) asm volatile("s_waitcnt vmcnt(8)" ::: "memory");
    else            asm volatile("s_waitcnt vmcnt(0)" ::: "memory");
    __builtin_amdgcn_sched_barrier(0);
    __builtin_amdgcn_s_barrier();
  }
#undef PHASE

  float4 bvs[4];
#pragma unroll
  for (int n = 0; n < 4; n++)
    bvs[n] = *(const float4*)&bias[col0 + wc * 64 + n * 16 + lhi * 4];
#pragma unroll
  for (int mq = 0; mq < 8; mq++){
    int grow = row0 + wr * 128 + mq * 16 + l16;
#pragma unroll
    for (int n = 0; n < 4; n++){
      int gcol = col0 + wc * 64 + n * 16 + lhi * 4;
      float4 vv = { acc[mq][n][0] + bvs[n].x, acc[mq][n][1] + bvs[n].y,
                    acc[mq][n][2] + bvs[n].z, acc[mq][n][3] + bvs[n].w };
      if constexpr (EPI == 1){
        float4 rv = *(const float4*)&R[(size_t)grow * ldr + gcol];
        vv.x += rv.x; vv.y += rv.y; vv.z += rv.z; vv.w += rv.w;
      }
      if constexpr (EPI == 2){
        vv.x = gelu_f(vv.x); vv.y = gelu_f(vv.y); vv.z = gelu_f(vv.z); vv.w = gelu_f(vv.w);
      }
      if constexpr (OUT_BF16){
        ushort4 o4 = { f2bf(vv.x), f2bf(vv.y), f2bf(vv.z), f2bf(vv.w) };
        *(ushort4*)&((u16*)Cv)[(size_t)grow * ldc + gcol] = o4;
      } else {
        *(float4*)&((float*)Cv)[(size_t)grow * ldc + gcol] = vv;
      }
    }
  }
}

__global__ __launch_bounds__(512, 2) void gemm_qkv_kernel(const u16* A, int lda, const u16* WT,
    const float* bias, const float* R, int ldr, void* Cv, int ldc, int K){
  gemm8_body<0, true>(A, lda, WT, bias, R, ldr, Cv, ldc, K);
}
__global__ __launch_bounds__(512, 2) void gemm_proj_kernel(const u16* A, int lda, const u16* WT,
    const float* bias, const float* R, int ldr, void* Cv, int ldc, int K){
  gemm8_body<1, false>(A, lda, WT, bias, R, ldr, Cv, ldc, K);
}
__global__ __launch_bounds__(512, 2) void gemm_fc1_kernel(const u16* A, int lda, const u16* WT,
    const float* bias, const float* R, int ldr, void* Cv, int ldc, int K){
  gemm8_body<2, true>(A, lda, WT, bias, R, ldr, Cv, ldc, K);
}
__global__ __launch_bounds__(512, 2) void gemm_fc2_kernel(const u16* A, int lda, const u16* WT,
    const float* bias, const float* R, int ldr, void* Cv, int ldc, int K){
  gemm8_body<1, false>(A, lda, WT, bias, R, ldr, Cv, ldc, K);
}

// ---------------- MFMA windowed attention + LePE (R15, unchanged) ----------------
__global__ __launch_bounds__(256) void attn_kernel(
    const u16* __restrict__ qkv, const float* __restrict__ lw,
    const float* __restrict__ lb, u16* __restrict__ out)
{
  __shared__ u16  Vt[4][32 * 76];
  __shared__ u16  Pl[4][64 * 76];
  __shared__ float Wl[9 * 256];
  __shared__ float Lb[256];
  const int tid = threadIdx.x;
  const int l   = tid & 63;
  const int w   = tid >> 6;
  const int l16 = l & 15, lhi = l >> 4;

  int win = blockIdx.x;
  int wx = win & 7, wy = (win >> 3) & 7, b = win >> 6;
  auto trow = [&](int tok){
    return (size_t)b * 4096 + (size_t)(wy * 8 + (tok >> 3)) * 64 + (wx * 8 + (tok & 7));
  };

  for (int i = tid; i < 2304; i += 256){
    int ch = i / 9, tp = i - ch * 9;
    Wl[tp * 256 + ch] = lw[i];
  }
  if (tid < 256) Lb[tid] = lb[tid];
  __syncthreads();

  u16* vt = Vt[w];
  u16* pl = Pl[w];

  for (int hi = 0; hi < 2; hi++){
    const int h = w + hi * 4;
    const int co = h * HD;

    {
      const u16* vp = qkv + trow(l) * 768 + 512 + co;
#pragma unroll
      for (int j = 0; j < 4; j++){
        short8 v8 = *(const short8*)(vp + j * 8);
#pragma unroll
        for (int e = 0; e < 8; e++)
          vt[(j * 8 + e) * 76 + l] = (u16)v8[e];
      }
    }

    short8 Qf[4], Kf[4];
#pragma unroll
    for (int m = 0; m < 4; m++){
      size_t r = trow(m * 16 + l16) * 768;
      Qf[m] = *(const short8*)(qkv + r + co + lhi * 8);
      Kf[m] = *(const short8*)(qkv + r + 256 + co + lhi * 8);
    }

    f32x4 s[4][4];
#pragma unroll
    for (int m = 0; m < 4; m++)
#pragma unroll
      for (int n = 0; n < 4; n++){
        f32x4 z = {0.f, 0.f, 0.f, 0.f};
        s[m][n] = mfma16(Kf[n], Qf[m], z);
      }

    float mx[4], sum[4], inv[4];
#pragma unroll
    for (int m = 0; m < 4; m++){
      float mm = -1e30f;
#pragma unroll
      for (int n = 0; n < 4; n++)
#pragma unroll
        for (int i = 0; i < 4; i++){
          s[m][n][i] *= SCALE_Q;
          mm = fmaxf(mm, s[m][n][i]);
        }
      mm = fmaxf(mm, __shfl_xor(mm, 16, 64));
      mm = fmaxf(mm, __shfl_xor(mm, 32, 64));
      mx[m] = mm;
      float ss = 0.f;
#pragma unroll
      for (int n = 0; n < 4; n++)
#pragma unroll
        for (int i = 0; i < 4; i++){
          float e = __expf(s[m][n][i] - mm);
          s[m][n][i] = e;
          ss += e;
        }
      ss += __shfl_xor(ss, 16, 64);
      ss += __shfl_xor(ss, 32, 64);
      sum[m] = ss;
      inv[m] = __builtin_amdgcn_rcpf(ss);
    }

#pragma unroll
    for (int m = 0; m < 4; m++){
      int q = m * 16 + l16;
#pragma unroll
      for (int n = 0; n < 4; n++){
        ushort4 p4 = { f2bf(s[m][n][0] * inv[m]), f2bf(s[m][n][1] * inv[m]),
                       f2bf(s[m][n][2] * inv[m]), f2bf(s[m][n][3] * inv[m]) };
        *(ushort4*)&pl[q * 76 + n * 16 + lhi * 4] = p4;
      }
    }
    short8 Pf[4][2], Vf[2][2];
#pragma unroll
    for (int m = 0; m < 4; m++)
#pragma unroll
      for (int st = 0; st < 2; st++)
        Pf[m][st] = *(const short8*)&pl[(m * 16 + l16) * 76 + st * 32 + lhi * 8];
#pragma unroll
    for (int df = 0; df < 2; df++)
#pragma unroll
      for (int st = 0; st < 2; st++)
        Vf[df][st] = *(const short8*)&vt[(df * 16 + l16) * 76 + st * 32 + lhi * 8];

    f32x4 o[4][2];
#pragma unroll
    for (int m = 0; m < 4; m++)
#pragma unroll
      for (int df = 0; df < 2; df++){
        f32x4 z = {0.f, 0.f, 0.f, 0.f};
        z = mfma16(Vf[df][0], Pf[m][0], z);
        o[m][df] = mfma16(Vf[df][1], Pf[m][1], z);
      }

#pragma unroll
    for (int m = 0; m < 4; m++){
      int q = m * 16 + l16;
      int py = q >> 3, px = q & 7;
#pragma unroll
      for (int df = 0; df < 2; df++){
        int dd = df * 16 + lhi * 4;
#pragma unroll
        for (int ky = 0; ky < 3; ky++){
          int yy = py + ky - 1;
          if (yy < 0 || yy >= 8) continue;
#pragma unroll
          for (int kx = 0; kx < 3; kx++){
            int xx = px + kx - 1;
            if (xx < 0 || xx >= 8) continue;
            int kp = yy * 8 + xx;
            ushort4 v4 = *(const ushort4*)(qkv + trow(kp) * 768 + 512 + co + dd);
            float4 wv = *(const float4*)&Wl[(ky * 3 + kx) * 256 + co + dd];
            o[m][df][0] += wv.x * bf2f(v4.x);
            o[m][df][1] += wv.y * bf2f(v4.y);
            o[m][df][2] += wv.z * bf2f(v4.z);
            o[m][df][3] += wv.w * bf2f(v4.w);
          }
        }
        float4 lbv = *(const float4*)&Lb[co + dd];
        ushort4 o4 = { f2bf(o[m][df][0] + lbv.x), f2bf(o[m][df][1] + lbv.y),
                       f2bf(o[m][df][2] + lbv.z), f2bf(o[m][df][3] + lbv.w) };
        *(ushort4*)&out[trow(q) * DIM + co + dd] = o4;
      }
    }
  }
}

// ---------------- full-image depthwise 3x3, vectorized (R14, unchanged) ----------------
__global__ __launch_bounds__(256) void convloc_kernel(const u16* __restrict__ img,
    const float* __restrict__ w, u16* __restrict__ out){
  __shared__ float Wl[9 * 256];
  int tid = threadIdx.x;
  for (int i = tid; i < 2304; i += 256){
    int ch = i / 9, tp = i - ch * 9;
    Wl[tp * 256 + ch] = w[i];
  }
  __syncthreads();
  int c  = (tid & 63) * 4;
  int pq = tid >> 6;
  int p  = blockIdx.x * 4 + pq;
  int b  = p >> 12;
  int pi = p & 4095;
  int y = pi >> 6, x = pi & 63;
  float a0 = 0.f, a1 = 0.f, a2 = 0.f, a3 = 0.f;
#pragma unroll
  for (int ky = 0; ky < 3; ky++){
    int yy = y + ky - 1;
    if (yy < 0 || yy >= 64) continue;
#pragma unroll
    for (int kx = 0; kx < 3; kx++){
      int xx = x + kx - 1;
      if (xx < 0 || xx >= 64) continue;
      ushort4 v = *(const ushort4*)&img[((size_t)b * 4096 + yy * 64 + xx) * DIM + C2 + c];
      float4 wv = *(const float4*)&Wl[(ky * 3 + kx) * 256 + c];
      a0 += wv.x * bf2f(v.x); a1 += wv.y * bf2f(v.y);
      a2 += wv.z * bf2f(v.z); a3 += wv.w * bf2f(v.w);
    }
  }
  ushort4 o4 = { f2bf(a0), f2bf(a1), f2bf(a2), f2bf(a3) };
  *(ushort4*)&out[((size_t)b * 4096 + pi) * DIM + C2 + c] = o4;
}

extern "C" void kernel_launch(void* const* d_in, const int* in_sizes, int n_in,
                              void* d_out, int out_size, void* d_ws, size_t ws_size,
                              hipStream_t stream){
  const float* x      = (const float*)d_in[0];
  const float* n1g    = (const float*)d_in[1];
  const float* n1b    = (const float*)d_in[2];
  const float* qkv_w  = (const float*)d_in[3];
  const float* qkv_b  = (const float*)d_in[4];
  const float* lepe_w = (const float*)d_in[5];
  const float* lepe_b = (const float*)d_in[6];
  const float* conv_w = (const float*)d_in[7];
  const float* proj_w = (const float*)d_in[8];
  const float* proj_b = (const float*)d_in[9];
  const float* n2g    = (const float*)d_in[10];
  const float* n2b    = (const float*)d_in[11];
  const float* fc1_w  = (const float*)d_in[12];
  const float* fc1_b  = (const float*)d_in[13];
  const float* fc2_w  = (const float*)d_in[14];
  const float* fc2_b  = (const float*)d_in[15];
  float* out = (float*)d_out;

  char* ws = (char*)d_ws;
  u16* img     = (u16*)(ws + 0);
  u16* qkvb    = (u16*)(ws + 33554432ull);
  u16* localb  = (u16*)(ws + 83886080ull);
  u16* y       = (u16*)(ws + 0);          // reuses img (dead after convloc)
  u16* h       = (u16*)(ws + 33554432ull);
  u16* qkv_wT  = (u16*)(ws + 167772160ull);
  u16* proj_wT = (u16*)(ws + 167772160ull + 393216ull);
  u16* fc1_wT  = (u16*)(ws + 167772160ull + 393216ull + 524288ull);
  u16* fc2_wT  = (u16*)(ws + 167772160ull + 393216ull + 524288ull + 2097152ull);
  float* xa    = (float*)d_out;

  prep_kernel<<<2496 + 8192, 256, 0, stream>>>(qkv_w, proj_w, fc1_w, fc2_w,
                                               qkv_wT, proj_wT, fc1_wT, fc2_wT,
                                               x, n1g, n1b, img);

  dim3 gq(3, 128);
  gemm_qkv_kernel<<<gq, 512, 0, stream>>>(img, DIM, qkv_wT, qkv_b, nullptr, 0, qkvb, 768, 256);

  attn_kernel<<<512, 256, 0, stream>>>(qkvb, lepe_w, lepe_b, localb);
  convloc_kernel<<<8192, 256, 0, stream>>>(img, conv_w, localb);

  dim3 gp(2, 128);
  gemm_proj_kernel<<<gp, 512, 0, stream>>>(localb, DIM, proj_wT, proj_b, x, DIM, xa, DIM, 512);

  ln_kernel<<<8192, 256, 0, stream>>>(xa, n2g, n2b, y);

  dim3 g1(8, 128);
  gemm_fc1_kernel<<<g1, 512, 0, stream>>>(y, DIM, fc1_wT, fc1_b, nullptr, 0, h, 2048, 512);

  dim3 g2(2, 128);
  gemm_fc2_kernel<<<g2, 512, 0, stream>>>(h, 2048, fc2_wT, fc2_b, xa, DIM, out, DIM, 2048);
}